// Round 1
// baseline (567.470 us; speedup 1.0000x reference)
//
#include <hip/hip_runtime.h>

#define BDIM 256
constexpr int B = 512, S = 480, F = 149;
constexpr int POSN = 72, VF = 5;
constexpr int STILE = 32;
constexpr int NTILES = S / STILE;          // 15
constexpr int NBLOCKS = B * NTILES;        // 7680

// W_MAT[24][5]: row k has WEIGHT[k]/wsum[PART[k]] in column PART[k], else 0.
__device__ __constant__ float WMAT[24][5] = {
    {0.f, 0.1f, 0.f, 0.f, 0.f},        // k0  p1 1/10
    {0.f, 0.2f, 0.f, 0.f, 0.f},        // k1  p1 2/10
    {0.f, 0.3f, 0.f, 0.f, 0.f},        // k2  p1 3/10
    {0.f, 0.4f, 0.f, 0.f, 0.f},        // k3  p1 4/10
    {0.f, 0.f, 0.1f, 0.f, 0.f},        // k4  p2 1/10
    {0.f, 0.f, 0.2f, 0.f, 0.f},        // k5  p2 2/10
    {0.f, 0.f, 0.3f, 0.f, 0.f},        // k6  p2 3/10
    {0.f, 0.f, 0.4f, 0.f, 0.f},        // k7  p2 4/10
    {1.0f/9.0f, 0.f, 0.f, 0.f, 0.f},   // k8  p0 1/9
    {1.0f/9.0f, 0.f, 0.f, 0.f, 0.f},   // k9  p0 1/9
    {1.0f/9.0f, 0.f, 0.f, 0.f, 0.f},   // k10 p0 1/9
    {1.0f/9.0f, 0.f, 0.f, 0.f, 0.f},   // k11 p0 1/9
    {1.0f/9.0f, 0.f, 0.f, 0.f, 0.f},   // k12 p0 1/9
    {0.f, 0.f, 0.f, 0.1f, 0.f},        // k13 p3 1/10
    {0.f, 0.f, 0.f, 0.2f, 0.f},        // k14 p3 2/10
    {0.f, 0.f, 0.f, 0.3f, 0.f},        // k15 p3 3/10
    {0.f, 0.f, 0.f, 0.4f, 0.f},        // k16 p3 4/10
    {0.f, 0.f, 0.f, 0.f, 0.1f},        // k17 p4 1/10
    {0.f, 0.f, 0.f, 0.f, 0.2f},        // k18 p4 2/10
    {0.f, 0.f, 0.f, 0.f, 0.3f},        // k19 p4 3/10
    {0.f, 0.f, 0.f, 0.f, 0.4f},        // k20 p4 4/10
    {1.0f/9.0f, 0.f, 0.f, 0.f, 0.f},   // k21 p0 1/9
    {2.0f/9.0f, 0.f, 0.f, 0.f, 0.f},   // k22 p0 2/9
    {1.0f/9.0f, 0.f, 0.f, 0.f, 0.f},   // k23 p0 1/9
};

__global__ __launch_bounds__(BDIM) void vel_loss_main(
    const float* __restrict__ P,    // predict_seq (B,S,F)
    const float* __restrict__ X1,   // _train_x1   (B,S,F) — only row s=0 used
    const float* __restrict__ TVF,  // _true_vel_factor (B,S+1,VF)
    const float* __restrict__ MEAN, // (F,)
    const float* __restrict__ STD,  // (F,)
    double* __restrict__ acc)       // acc[0]=sum1, acc[1]=sum0, acc[2]=sum2
{
    __shared__ float rows[(STILE + 1) * F];   // 33 rows of 149
    __shared__ float norms[STILE * 24];
    __shared__ float stdp[POSN], mv[POSN], isv[POSN];
    __shared__ float mf[VF], isf[VF];
    __shared__ float red[4][3];

    const int t = threadIdx.x;
    const int bid = blockIdx.x;
    const int b = bid / NTILES;
    const int s0 = (bid - b * NTILES) * STILE;

    // ---- stage normalization params ----
    if (t < POSN) {
        stdp[t] = STD[t];
        mv[t]   = MEAN[POSN + t];
        isv[t]  = 1.0f / STD[POSN + t];
    } else if (t < POSN + VF) {
        int p = t - POSN;
        mf[p]  = MEAN[144 + p];
        isf[p] = 1.0f / STD[144 + p];
    }

    // ---- stage rows: lds row r corresponds to global step s0-1+r ----
    // rows 1..32 = predict_seq[b, s0 .. s0+31, :] — contiguous 32*149 floats
    const float* srcA = P + ((size_t)b * S + s0) * F;
    for (int i = t; i < STILE * F; i += BDIM) rows[F + i] = srcA[i];
    // row 0 = predecessor: predict_seq[b, s0-1, :] or _train_x1[b, 0, :]
    const float* src0 = (s0 > 0) ? (P + ((size_t)b * S + (s0 - 1)) * F)
                                 : (X1 + (size_t)b * S * F);
    for (int i = t; i < F; i += BDIM) rows[i] = src0[i];

    __syncthreads();

    float sum0 = 0.f, sum1 = 0.f, sum2 = 0.f;

    // ---- phase 1: velocities, velocity-MSE partials, norms ----
    // 32 s-steps x 24 joint-groups = 768 items, 3 per thread
    #pragma unroll
    for (int it = 0; it < 3; ++it) {
        const int item = t + it * BDIM;
        const int sl = item / 24;
        const int k  = item - sl * 24;
        const int s  = s0 + sl;
        const float* cur = &rows[(sl + 1) * F];
        const float* prv = &rows[sl * F];
        float nsq = 0.f;
        #pragma unroll
        for (int c = 0; c < 3; ++c) {
            const int j = 3 * k + c;
            const float tv = (cur[j] - prv[j]) * stdp[j];
            nsq = fmaf(tv, tv, nsq);
            const float pv = cur[77 + j];         // pred_vel column = F-72+j
            if (s == 0) {
                sum0 += pv * pv;                  // mse(pred_vel[:,0], 0)
            } else {
                const float tnv = (tv - mv[j]) * isv[j];
                const float d = pv - tnv;
                sum1 = fmaf(d, d, sum1);
            }
        }
        norms[sl * 24 + k] = sqrtf(nsq);
    }

    __syncthreads();

    // ---- phase 2: 24 -> 5 weighted norm factors + factor-MSE ----
    if (t < STILE * VF) {                          // 160 threads
        const int sl = t / VF, p = t - sl * VF;
        const int s = s0 + sl;
        if (s >= 1) {                              // s=0 factor excluded
            float a = 0.f;
            #pragma unroll
            for (int k = 0; k < 24; ++k)
                a = fmaf(norms[sl * 24 + k], WMAT[k][p], a);
            const float tvf = (a - mf[p]) * isf[p];
            const float tr  = TVF[((size_t)b * (S + 1) + s) * VF + p];
            const float d = tr - tvf;
            sum2 = fmaf(d, d, sum2);
        }
    }

    // ---- block reduction ----
    #pragma unroll
    for (int off = 32; off > 0; off >>= 1) {
        sum0 += __shfl_down(sum0, off, 64);
        sum1 += __shfl_down(sum1, off, 64);
        sum2 += __shfl_down(sum2, off, 64);
    }
    const int wave = t >> 6, lane = t & 63;
    if (lane == 0) { red[wave][0] = sum0; red[wave][1] = sum1; red[wave][2] = sum2; }
    __syncthreads();
    if (t == 0) {
        const float b0 = red[0][0] + red[1][0] + red[2][0] + red[3][0];
        const float b1 = red[0][1] + red[1][1] + red[2][1] + red[3][1];
        const float b2 = red[0][2] + red[1][2] + red[2][2] + red[3][2];
        atomicAdd(&acc[0], (double)b1);
        atomicAdd(&acc[1], (double)b0);
        atomicAdd(&acc[2], (double)b2);
    }
}

__global__ void vel_loss_final(const double* __restrict__ acc,
                               float* __restrict__ out)
{
    const double mse1 = acc[0] / (double)((long long)B * (S - 1) * 72); // 512*479*72
    const double mse0 = acc[1] / (double)((long long)B * 72);           // 512*72
    const double mse2 = acc[2] / (double)((long long)B * (S - 1) * 5);  // 512*479*5
    // loss = 2*(10*mse1 + 20*mse0) + 1.5*(10*mse2)
    out[0] = (float)(20.0 * mse1 + 40.0 * mse0 + 15.0 * mse2);
}

extern "C" void kernel_launch(void* const* d_in, const int* in_sizes, int n_in,
                              void* d_out, int out_size, void* d_ws, size_t ws_size,
                              hipStream_t stream) {
    const float* P    = (const float*)d_in[0];  // predict_seq
    const float* X1   = (const float*)d_in[1];  // _train_x1
    // d_in[2] (_train_x2) unused
    const float* TVF  = (const float*)d_in[3];  // _true_vel_factor
    const float* MEAN = (const float*)d_in[4];
    const float* STD  = (const float*)d_in[5];

    double* acc = (double*)d_ws;
    hipMemsetAsync(acc, 0, 3 * sizeof(double), stream);
    vel_loss_main<<<NBLOCKS, BDIM, 0, stream>>>(P, X1, TVF, MEAN, STD, acc);
    vel_loss_final<<<1, 1, 0, stream>>>(acc, (float*)d_out);
}

// Round 3
// 343.622 us; speedup vs baseline: 1.6514x; 1.6514x over previous
//
#include <hip/hip_runtime.h>

#define BDIM 256
constexpr int B = 512, S = 480, F = 149;
constexpr int POSN = 72, VF = 5;
constexpr int STILE = 32;
constexpr int NTILES = S / STILE;          // 15
constexpr int NBLOCKS = B * NTILES;        // 7680
constexpr int ROWELE = (STILE + 1) * F;    // 4917

// W_MAT[24][5]: row k has WEIGHT[k]/wsum[PART[k]] in column PART[k], else 0.
__device__ __constant__ float WMAT[24][5] = {
    {0.f, 0.1f, 0.f, 0.f, 0.f},
    {0.f, 0.2f, 0.f, 0.f, 0.f},
    {0.f, 0.3f, 0.f, 0.f, 0.f},
    {0.f, 0.4f, 0.f, 0.f, 0.f},
    {0.f, 0.f, 0.1f, 0.f, 0.f},
    {0.f, 0.f, 0.2f, 0.f, 0.f},
    {0.f, 0.f, 0.3f, 0.f, 0.f},
    {0.f, 0.f, 0.4f, 0.f, 0.f},
    {1.0f/9.0f, 0.f, 0.f, 0.f, 0.f},
    {1.0f/9.0f, 0.f, 0.f, 0.f, 0.f},
    {1.0f/9.0f, 0.f, 0.f, 0.f, 0.f},
    {1.0f/9.0f, 0.f, 0.f, 0.f, 0.f},
    {1.0f/9.0f, 0.f, 0.f, 0.f, 0.f},
    {0.f, 0.f, 0.f, 0.1f, 0.f},
    {0.f, 0.f, 0.f, 0.2f, 0.f},
    {0.f, 0.f, 0.f, 0.3f, 0.f},
    {0.f, 0.f, 0.f, 0.4f, 0.f},
    {0.f, 0.f, 0.f, 0.f, 0.1f},
    {0.f, 0.f, 0.f, 0.f, 0.2f},
    {0.f, 0.f, 0.f, 0.f, 0.3f},
    {0.f, 0.f, 0.f, 0.f, 0.4f},
    {1.0f/9.0f, 0.f, 0.f, 0.f, 0.f},
    {2.0f/9.0f, 0.f, 0.f, 0.f, 0.f},
    {1.0f/9.0f, 0.f, 0.f, 0.f, 0.f},
};

__global__ __launch_bounds__(BDIM) void vel_loss_main(
    const float* __restrict__ P,    // predict_seq (B,S,F)
    const float* __restrict__ X1,   // _train_x1   (B,S,F) — only row s=0 used
    const float* __restrict__ TVF,  // _true_vel_factor (B,S+1,VF)
    const float* __restrict__ MEAN, // (F,)
    const float* __restrict__ STD,  // (F,)
    float* __restrict__ part)       // 3*NBLOCKS partials (column-major)
{
    __shared__ __align__(16) float rows[ROWELE + 4]; // 33 rows of 149 + pad
    __shared__ float norms[STILE * 24];
    __shared__ float stdp[POSN], mv[POSN], isv[POSN];
    __shared__ float mf[VF], isf[VF];
    __shared__ float red[4][3];

    const int t = threadIdx.x;
    const int bid = blockIdx.x;
    const int b = bid / NTILES;
    const int s0 = (bid - b * NTILES) * STILE;

    // ---- stage normalization params (issued early, L2-resident) ----
    if (t < POSN) {
        stdp[t] = STD[t];
        mv[t]   = MEAN[POSN + t];
        isv[t]  = 1.0f / STD[POSN + t];
    } else if (t < POSN + VF) {
        int p2 = t - POSN;
        mf[p2]  = MEAN[144 + p2];
        isf[p2] = 1.0f / STD[144 + p2];
    }

    // ---- prefetch true_vel_factor operand for phase 2 ----
    float tvf_true = 0.f;
    {
        const int sl = t / VF, p2 = t - sl * VF;
        const int s  = s0 + sl;
        if (t < STILE * VF && s >= 1)
            tvf_true = TVF[((size_t)b * (S + 1) + s) * VF + p2];
    }

    // ---- stage rows (vectorized, co-aligned float4 -> ds_write_b128) ----
    // LDS row r, float j lives at rows[pad + r*F + j].
    const float* g; int n, L;
    if (s0 > 0) {        // rows 0..32 = P[b, s0-1 .. s0+31] contiguous
        g = P + ((size_t)b * S + (s0 - 1)) * F; n = ROWELE; L = 0;
    } else {             // rows 1..32 = P[b, 0..31]; row 0 from X1 separately
        g = P + (size_t)b * S * F;              n = STILE * F; L = F;
    }
    const int a0  = (4 - (int)((((uintptr_t)g) >> 2) & 3)) & 3; // dwords to 16B
    const int pad = (-(L + a0)) & 3;                            // co-align LDS

    // head scalars
    if (t < a0) rows[pad + L + t] = g[t];
    // aligned float4 body
    {
        const float4* g4 = (const float4*)(g + a0);
        float* dst = &rows[pad + L + a0];
        const int n4 = (n - a0) >> 2;
        #pragma unroll 8
        for (int i = t; i < n4; i += BDIM)
            *(float4*)(dst + 4 * i) = g4[i];
        // tail scalars
        for (int i = a0 + 4 * n4 + t; i < n; i += BDIM)
            rows[pad + L + i] = g[i];
    }
    // predecessor row for s0==0 blocks (X1[b,0,:], scalar — one round)
    if (s0 == 0) {
        const float* x = X1 + (size_t)b * S * F;
        if (t < F) rows[pad + t] = x[t];
    }

    __syncthreads();

    float sum0 = 0.f, sum1 = 0.f, sum2 = 0.f;

    // ---- phase 1: velocities, velocity-MSE partials, norms ----
    #pragma unroll
    for (int it = 0; it < 3; ++it) {
        const int item = t + it * BDIM;
        const int sl = item / 24;
        const int k  = item - sl * 24;
        const int s  = s0 + sl;
        const float* cur = &rows[pad + (sl + 1) * F];
        const float* prv = &rows[pad + sl * F];
        float nsq = 0.f;
        #pragma unroll
        for (int c = 0; c < 3; ++c) {
            const int j = 3 * k + c;
            const float tv = (cur[j] - prv[j]) * stdp[j];
            nsq = fmaf(tv, tv, nsq);
            const float pv = cur[77 + j];         // pred_vel column
            if (s == 0) {
                sum0 += pv * pv;
            } else {
                const float tnv = (tv - mv[j]) * isv[j];
                const float d = pv - tnv;
                sum1 = fmaf(d, d, sum1);
            }
        }
        norms[sl * 24 + k] = sqrtf(nsq);
    }

    __syncthreads();

    // ---- phase 2: 24 -> 5 weighted norm factors + factor-MSE ----
    if (t < STILE * VF) {
        const int sl = t / VF, p2 = t - sl * VF;
        const int s = s0 + sl;
        if (s >= 1) {
            float a = 0.f;
            #pragma unroll
            for (int k = 0; k < 24; ++k)
                a = fmaf(norms[sl * 24 + k], WMAT[k][p2], a);
            const float tvf = (a - mf[p2]) * isf[p2];
            const float d = tvf_true - tvf;
            sum2 = fmaf(d, d, sum2);
        }
    }

    // ---- block reduction ----
    #pragma unroll
    for (int off = 32; off > 0; off >>= 1) {
        sum0 += __shfl_down(sum0, off, 64);
        sum1 += __shfl_down(sum1, off, 64);
        sum2 += __shfl_down(sum2, off, 64);
    }
    const int wave = t >> 6, lane = t & 63;
    if (lane == 0) { red[wave][0] = sum0; red[wave][1] = sum1; red[wave][2] = sum2; }
    __syncthreads();
    if (t == 0) {
        const float b0 = red[0][0] + red[1][0] + red[2][0] + red[3][0];
        const float b1 = red[0][1] + red[1][1] + red[2][1] + red[3][1];
        const float b2 = red[0][2] + red[1][2] + red[2][2] + red[3][2];
        part[bid]               = b1;   // sum1 (velocity MSE, s>=1)
        part[NBLOCKS + bid]     = b0;   // sum0 (s==0 pred_vel)
        part[2 * NBLOCKS + bid] = b2;   // sum2 (factor MSE)
    }
}

__global__ __launch_bounds__(1024) void vel_loss_final(
    const float* __restrict__ part, float* __restrict__ out)
{
    const int t = threadIdx.x;
    double s1 = 0.0, s0 = 0.0, s2 = 0.0;
    for (int i = t; i < NBLOCKS; i += 1024) {
        s1 += (double)part[i];
        s0 += (double)part[NBLOCKS + i];
        s2 += (double)part[2 * NBLOCKS + i];
    }
    #pragma unroll
    for (int off = 32; off > 0; off >>= 1) {
        s1 += __shfl_down(s1, off, 64);
        s0 += __shfl_down(s0, off, 64);
        s2 += __shfl_down(s2, off, 64);
    }
    __shared__ double red[16][3];
    const int wave = t >> 6, lane = t & 63;
    if (lane == 0) { red[wave][0] = s1; red[wave][1] = s0; red[wave][2] = s2; }
    __syncthreads();
    if (t == 0) {
        double a1 = 0, a0 = 0, a2 = 0;
        #pragma unroll
        for (int w = 0; w < 16; ++w) { a1 += red[w][0]; a0 += red[w][1]; a2 += red[w][2]; }
        const double mse1 = a1 / (double)((long long)B * (S - 1) * 72);
        const double mse0 = a0 / (double)((long long)B * 72);
        const double mse2 = a2 / (double)((long long)B * (S - 1) * 5);
        out[0] = (float)(20.0 * mse1 + 40.0 * mse0 + 15.0 * mse2);
    }
}

extern "C" void kernel_launch(void* const* d_in, const int* in_sizes, int n_in,
                              void* d_out, int out_size, void* d_ws, size_t ws_size,
                              hipStream_t stream) {
    const float* P    = (const float*)d_in[0];  // predict_seq
    const float* X1   = (const float*)d_in[1];  // _train_x1
    // d_in[2] (_train_x2) unused
    const float* TVF  = (const float*)d_in[3];  // _true_vel_factor
    const float* MEAN = (const float*)d_in[4];
    const float* STD  = (const float*)d_in[5];

    float* part = (float*)d_ws;                 // 3*NBLOCKS floats
    vel_loss_main<<<NBLOCKS, BDIM, 0, stream>>>(P, X1, TVF, MEAN, STD, part);
    vel_loss_final<<<1, 1024, 0, stream>>>(part, (float*)d_out);
}